// Round 2
// baseline (114.340 us; speedup 1.0000x reference)
//
#include <hip/hip_runtime.h>

#define EPSILON 5.0f

constexpr int BLOCKS  = 2048;     // 8 blocks/CU on 256 CUs
constexpr int THREADS = 256;      // 4 waves/block

// Stage 1: each 16-lane group owns one row (4 rows per wave per iteration).
// Lane `sub` of a group loads float4 at [sub + 16k], k=0..7 -> 256B contiguous
// per group per instruction, fully coalesced. Labels prefetched 1 iter ahead
// so the label->means dependent chain is off the critical path.
__global__ __launch_bounds__(THREADS) void ncl_partial_kernel(
    const float* __restrict__ features,
    const float* __restrict__ means,
    const int* __restrict__ labels,
    float* __restrict__ partials,
    int B)
{
    const int lane = threadIdx.x & 63;
    const int sub  = lane & 15;              // lane within 16-group
    const int g    = lane >> 4;              // group 0..3 (row within quad)
    const int globalWave = blockIdx.x * (THREADS >> 6) + (threadIdx.x >> 6);
    const int totalWaves = gridDim.x * (THREADS >> 6);
    const int nQuads = (B + 3) >> 2;

    float wsum = 0.0f;

    // prefetch labels for the first iteration (4 consecutive dwords per wave)
    int q   = globalWave;
    int row = q * 4 + g;
    int cls = (q < nQuads && row < B) ? labels[row] : 0;

    for (; q < nQuads; q += totalWaves) {
        row = q * 4 + g;
        const bool valid = (row < B);

        // prefetch next iteration's label NOW (breaks label->means dependency)
        const int nq   = q + totalWaves;
        const int nrow = nq * 4 + g;
        const int ncls = (nq < nQuads && nrow < B) ? labels[nrow] : 0;

        float acc = 0.0f;
        if (valid) {
            const float4* f = reinterpret_cast<const float4*>(features) + (size_t)row * 128;
            const float4* m = reinterpret_cast<const float4*>(means)    + (size_t)cls * 128;
            #pragma unroll
            for (int k = 0; k < 8; ++k) {
                const float4 fv = f[sub + 16 * k];   // HBM stream
                const float4 mv = m[sub + 16 * k];   // L2-resident (means = 2 MiB)
                const float dx = fv.x - mv.x;
                const float dy = fv.y - mv.y;
                const float dz = fv.z - mv.z;
                const float dw = fv.w - mv.w;
                acc = fmaf(dx, dx, fmaf(dy, dy, fmaf(dz, dz, fmaf(dw, dw, acc))));
            }
        }

        // reduce within each 16-lane group (4 rows reduced by 4 shuffles total)
        #pragma unroll
        for (int off = 8; off > 0; off >>= 1)
            acc += __shfl_xor(acc, off, 64);

        if (sub == 0 && valid)
            wsum += fmaxf(EPSILON - sqrtf(acc), 0.0f);   // 4 lanes in parallel

        cls = ncls;
    }

    // wave reduce: wsum is nonzero only on lanes 0,16,32,48; rest hold 0.0
    #pragma unroll
    for (int off = 32; off > 0; off >>= 1)
        wsum += __shfl_xor(wsum, off, 64);

    __shared__ float s[THREADS >> 6];
    const int wv = threadIdx.x >> 6;
    if (lane == 0) s[wv] = wsum;
    __syncthreads();
    if (threadIdx.x == 0) {
        float t = 0.0f;
        #pragma unroll
        for (int i = 0; i < (THREADS >> 6); ++i) t += s[i];
        partials[blockIdx.x] = t;
    }
}

// Stage 2: single block reduces BLOCKS partials, writes mean.
__global__ __launch_bounds__(THREADS) void ncl_final_kernel(
    const float* __restrict__ partials,
    int n,
    float* __restrict__ out,
    float invB)
{
    float t = 0.0f;
    for (int i = threadIdx.x; i < n; i += THREADS) t += partials[i];

    #pragma unroll
    for (int off = 32; off > 0; off >>= 1)
        t += __shfl_xor(t, off, 64);

    __shared__ float s[THREADS >> 6];
    const int lane = threadIdx.x & 63;
    const int wv   = threadIdx.x >> 6;
    if (lane == 0) s[wv] = t;
    __syncthreads();
    if (threadIdx.x == 0) {
        float acc = 0.0f;
        #pragma unroll
        for (int i = 0; i < (THREADS >> 6); ++i) acc += s[i];
        out[0] = acc * invB;
    }
}

extern "C" void kernel_launch(void* const* d_in, const int* in_sizes, int n_in,
                              void* d_out, int out_size, void* d_ws, size_t ws_size,
                              hipStream_t stream) {
    const float* features = (const float*)d_in[0];
    const float* means    = (const float*)d_in[1];
    const int*   labels   = (const int*)d_in[2];
    float* out = (float*)d_out;

    const int B = in_sizes[2];        // one label per row
    float* partials = (float*)d_ws;   // BLOCKS floats

    ncl_partial_kernel<<<BLOCKS, THREADS, 0, stream>>>(features, means, labels,
                                                       partials, B);
    ncl_final_kernel<<<1, THREADS, 0, stream>>>(partials, BLOCKS, out,
                                                1.0f / (float)B);
}

// Round 4
// 102.446 us; speedup vs baseline: 1.1161x; 1.1161x over previous
//
#include <hip/hip_runtime.h>

#define EPSILON 5.0f

constexpr int BLOCKS  = 2048;     // 8 blocks/CU on 256 CUs
constexpr int THREADS = 256;      // 4 waves/block

typedef float fx4 __attribute__((ext_vector_type(4)));   // native vector: OK for nontemporal builtins

// Stage 1: one wave per row, explicitly software-pipelined:
//   - features/means for row i+1 are issued BEFORE row i's compute,
//     so 4 vector loads stay in flight during the FMA/reduce tail.
//   - labels are prefetched 2 iterations ahead (label -> means addr chain).
//   - features use nontemporal loads (zero reuse; keep L1 for means).
// Live data: 8 fx4 = 32 VGPRs -> high occupancy.
__global__ __launch_bounds__(THREADS) void ncl_partial_kernel(
    const float* __restrict__ features,
    const float* __restrict__ means,
    const int* __restrict__ labels,
    float* __restrict__ partials,
    int B)
{
    const int lane = threadIdx.x & 63;
    const int globalWave = blockIdx.x * (THREADS >> 6) + (threadIdx.x >> 6);
    const int totalWaves = gridDim.x * (THREADS >> 6);

    const fx4* __restrict__ F = reinterpret_cast<const fx4*>(features);
    const fx4* __restrict__ M = reinterpret_cast<const fx4*>(means);

    float wsum = 0.0f;   // meaningful on lane 0 only

    int row = globalWave;
    int cls0 = (row < B) ? labels[row] : 0;
    {
        const int r1 = row + totalWaves;
        int cls1 = (r1 < B) ? labels[r1] : 0;

        // prologue loads for the first row
        fx4 f0 = {0,0,0,0}, f1 = {0,0,0,0}, m0 = {0,0,0,0}, m1 = {0,0,0,0};
        if (row < B) {
            const fx4* f = F + (size_t)row  * 128;
            const fx4* m = M + (size_t)cls0 * 128;
            f0 = __builtin_nontemporal_load(f + lane);
            f1 = __builtin_nontemporal_load(f + lane + 64);
            m0 = m[lane];
            m1 = m[lane + 64];
        }

        while (row < B) {
            const int nrow = row + totalWaves;

            // ---- prefetch next row's data (label already in cls1) ----
            fx4 nf0 = {0,0,0,0}, nf1 = {0,0,0,0}, nm0 = {0,0,0,0}, nm1 = {0,0,0,0};
            if (nrow < B) {
                const fx4* f = F + (size_t)nrow * 128;
                const fx4* m = M + (size_t)cls1 * 128;
                nf0 = __builtin_nontemporal_load(f + lane);
                nf1 = __builtin_nontemporal_load(f + lane + 64);
                nm0 = m[lane];
                nm1 = m[lane + 64];
            }
            // prefetch label two ahead
            const int r2   = row + 2 * totalWaves;
            const int cls2 = (r2 < B) ? labels[r2] : 0;

            // ---- compute current row (next row's loads in flight) ----
            fx4 d0 = f0 - m0;
            fx4 d1 = f1 - m1;
            float ax = d0.x * d0.x, ay = d0.y * d0.y,
                  az = d0.z * d0.z, aw = d0.w * d0.w;
            ax = fmaf(d1.x, d1.x, ax); ay = fmaf(d1.y, d1.y, ay);
            az = fmaf(d1.z, d1.z, az); aw = fmaf(d1.w, d1.w, aw);
            float acc = (ax + ay) + (az + aw);

            #pragma unroll
            for (int off = 32; off > 0; off >>= 1)
                acc += __shfl_xor(acc, off, 64);

            if (lane == 0)
                wsum += fmaxf(EPSILON - sqrtf(acc), 0.0f);

            // ---- rotate pipeline ----
            f0 = nf0; f1 = nf1; m0 = nm0; m1 = nm1;
            cls1 = cls2;
            row  = nrow;
        }
    }

    __shared__ float s[THREADS >> 6];
    const int wv = threadIdx.x >> 6;
    if (lane == 0) s[wv] = wsum;
    __syncthreads();
    if (threadIdx.x == 0) {
        float t = 0.0f;
        #pragma unroll
        for (int i = 0; i < (THREADS >> 6); ++i) t += s[i];
        partials[blockIdx.x] = t;
    }
}

// Stage 2: single block reduces BLOCKS partials, writes mean.
__global__ __launch_bounds__(THREADS) void ncl_final_kernel(
    const float* __restrict__ partials,
    int n,
    float* __restrict__ out,
    float invB)
{
    float t = 0.0f;
    for (int i = threadIdx.x; i < n; i += THREADS) t += partials[i];

    #pragma unroll
    for (int off = 32; off > 0; off >>= 1)
        t += __shfl_xor(t, off, 64);

    __shared__ float s[THREADS >> 6];
    const int lane = threadIdx.x & 63;
    const int wv   = threadIdx.x >> 6;
    if (lane == 0) s[wv] = t;
    __syncthreads();
    if (threadIdx.x == 0) {
        float acc = 0.0f;
        #pragma unroll
        for (int i = 0; i < (THREADS >> 6); ++i) acc += s[i];
        out[0] = acc * invB;
    }
}

extern "C" void kernel_launch(void* const* d_in, const int* in_sizes, int n_in,
                              void* d_out, int out_size, void* d_ws, size_t ws_size,
                              hipStream_t stream) {
    const float* features = (const float*)d_in[0];
    const float* means    = (const float*)d_in[1];
    const int*   labels   = (const int*)d_in[2];
    float* out = (float*)d_out;

    const int B = in_sizes[2];        // one label per row
    float* partials = (float*)d_ws;   // BLOCKS floats

    ncl_partial_kernel<<<BLOCKS, THREADS, 0, stream>>>(features, means, labels,
                                                       partials, B);
    ncl_final_kernel<<<1, THREADS, 0, stream>>>(partials, BLOCKS, out,
                                                1.0f / (float)B);
}